// Round 1
// 355.497 us; speedup vs baseline: 1.0429x; 1.0429x over previous
//
#include <hip/hip_runtime.h>
#include <math.h>

// Problem constants (fixed by setup_inputs)
#define DD 128
#define NROWS 769          // 256 input-enc + 256 output-enc + 256 gate + 1 zero
#define T_TOTAL 524288

typedef float vfloat4 __attribute__((ext_vector_type(4)));

// ws layout (floats):
//   Wt      [3][128][128] @ 0          (Wt[part][k][j] = W[j][part*128+k])
//   Psrc    [NROWS][DD]   @ 49152
//   Pdst    [NROWS][DD]   @ 49152 +  98432
//   Prel    [2][DD]       @ 49152 + 196864
// total ~= 246272 floats ~= 0.99 MB (fits easily in ws)

#define WT_OFF    0
#define PSRC_OFF  (3 * DD * DD)
#define PDST_OFF  (PSRC_OFF + NROWS * DD)
#define PREL_OFF  (PDST_OFF + NROWS * DD)

// Transpose W (128 x 384, row-major) into three 128x128 column-major-ish
// blocks so the precompute loop reads coalesced along j.
__global__ void transposeW(const float* __restrict__ W, float* __restrict__ Wt) {
    int k = blockIdx.x;    // 0..127
    int j = threadIdx.x;   // 0..127
    Wt[0 * DD * DD + k * DD + j] = W[j * 384 + k];         // src part
    Wt[1 * DD * DD + k * DD + j] = W[j * 384 + 128 + k];   // rel part
    Wt[2 * DD * DD + k * DD + j] = W[j * 384 + 256 + k];   // dst part
}

// One block per table row (769 node rows + 2 rel rows). Builds the embedding
// row in LDS, then computes the W projection with coalesced Wt reads.
__global__ __launch_bounds__(DD) void prep(
    const float* __restrict__ gate_emb, const float* __restrict__ edge_emb,
    const float* __restrict__ b, const float* __restrict__ Wt,
    float* __restrict__ Psrc, float* __restrict__ Pdst,
    float* __restrict__ Prel) {
    __shared__ float row[DD];
    int r = blockIdx.x;
    int j = threadIdx.x;

    if (r < NROWS) {
        float v;
        if (r < 512) {
            int p = r & 255;   // input/output sinusoid tables are identical
            int i = j >> 1;
            float div = expf(-logf(10000.0f) * (2.0f * (float)i) / 128.0f);
            float ang = (float)p * div;
            v = (j & 1) ? cosf(ang) : sinf(ang);
        } else if (r < 768) {
            v = gate_emb[(r - 512) * DD + j];
        } else {
            v = 0.0f;
        }
        row[j] = v;
        __syncthreads();
        const float* Ws = Wt;                 // src part
        const float* Wd = Wt + 2 * DD * DD;   // dst part
        float s = 0.0f, d = 0.0f;
#pragma unroll 8
        for (int k = 0; k < DD; ++k) {
            float e = row[k];                          // LDS broadcast (free)
            s = fmaf(e, Ws[k * DD + j], s);            // coalesced
            d = fmaf(e, Wd[k * DD + j], d);
        }
        Psrc[r * DD + j] = s;
        Pdst[r * DD + j] = d;
    } else {
        int rr = r - NROWS;                   // 0..1
        row[j] = edge_emb[rr * DD + j];
        __syncthreads();
        const float* Wr = Wt + 1 * DD * DD;   // rel part
        float s = b[j];
#pragma unroll 8
        for (int k = 0; k < DD; ++k) s = fmaf(row[k], Wr[k * DD + j], s);
        Prel[rr * DD + j] = s;
    }
}

// out[t] = Psrc[fs(t)] + Prel[rel(t)] + Pdst[fd(t)]
// 32 lanes per row (float4 each), 8 rows per 256-thread block, 4 rows per
// thread (batched: all idx loads -> all table gathers -> all stores) to get
// 4x the loads in flight per wave (MLP probe vs. the write-roofline model).
__global__ __launch_bounds__(256) void gather_add(
    const int* __restrict__ src_idx, const int* __restrict__ src_type,
    const int* __restrict__ rel, const int* __restrict__ dst_idx,
    const int* __restrict__ dst_type,
    const vfloat4* __restrict__ Psrc, const vfloat4* __restrict__ Pdst,
    const vfloat4* __restrict__ Prel, vfloat4* __restrict__ out) {
    int tid = threadIdx.x;
    int lane = tid & 31;                       // which float4 of the 128-dim row
    int rowInBlk = tid >> 5;                   // 0..7
    int tbase = blockIdx.x * 32 + rowInBlk;    // block covers 32 consecutive rows

    int st[4], si[4], dt[4], di[4], rl[4];
#pragma unroll
    for (int i = 0; i < 4; ++i) {
        int t = tbase + 8 * i;
        st[i] = src_type[t];
        si[i] = src_idx[t];
        dt[i] = dst_type[t];
        di[i] = dst_idx[t];
        rl[i] = rel[t];
    }

    vfloat4 a[4], r4[4], c[4];
#pragma unroll
    for (int i = 0; i < 4; ++i) {
        int fs = (st[i] == 3) ? 768 : st[i] * 256 + si[i];  // offsets {0,256,512}, zero row 768
        int fd = (dt[i] == 3) ? 768 : dt[i] * 256 + di[i];
        a[i]  = Psrc[fs * 32 + lane];
        c[i]  = Pdst[fd * 32 + lane];
        r4[i] = Prel[rl[i] * 32 + lane];
    }

#pragma unroll
    for (int i = 0; i < 4; ++i) {
        int t = tbase + 8 * i;
        vfloat4 o = a[i] + r4[i] + c[i];
        // Nontemporal: don't let the 256MB output stream evict the hot P-tables in L2.
        __builtin_nontemporal_store(o, &out[t * 32 + lane]);
    }
}

extern "C" void kernel_launch(void* const* d_in, const int* in_sizes, int n_in,
                              void* d_out, int out_size, void* d_ws, size_t ws_size,
                              hipStream_t stream) {
    const float* gate_emb = (const float*)d_in[0];
    const float* edge_emb = (const float*)d_in[1];
    const float* W        = (const float*)d_in[2];
    const float* b        = (const float*)d_in[3];
    const int* src_idx    = (const int*)d_in[4];
    const int* src_type   = (const int*)d_in[5];
    const int* rel        = (const int*)d_in[6];
    const int* dst_idx    = (const int*)d_in[7];
    const int* dst_type   = (const int*)d_in[8];
    // d_in[9], d_in[10]: num_input_nodes / num_output_nodes == 256 (fixed)

    float* ws   = (float*)d_ws;
    float* Wt   = ws + WT_OFF;
    float* Psrc = ws + PSRC_OFF;
    float* Pdst = ws + PDST_OFF;
    float* Prel = ws + PREL_OFF;

    transposeW<<<DD, DD, 0, stream>>>(W, Wt);
    prep<<<NROWS + 2, DD, 0, stream>>>(gate_emb, edge_emb, b, Wt,
                                       Psrc, Pdst, Prel);
    gather_add<<<T_TOTAL / 32, 256, 0, stream>>>(
        src_idx, src_type, rel, dst_idx, dst_type,
        (const vfloat4*)Psrc, (const vfloat4*)Pdst, (const vfloat4*)Prel,
        (vfloat4*)d_out);
}

// Round 2
// 338.657 us; speedup vs baseline: 1.0948x; 1.0497x over previous
//
#include <hip/hip_runtime.h>
#include <math.h>

// Problem constants (fixed by setup_inputs)
#define DD 128
#define NROWS 769          // 256 input-enc + 256 output-enc + 256 gate + 1 zero
#define T_TOTAL 524288

typedef float vfloat4 __attribute__((ext_vector_type(4)));

// ws layout (floats):
//   Wt      [3][128][128] @ 0          (Wt[part][k][j] = W[j][part*128+k])
//   Psrc    [NROWS][DD]   @ 49152
//   Pdst    [NROWS][DD]   @ 49152 +  98432
//   Prel    [2][DD]       @ 49152 + 196864
// total ~= 246272 floats ~= 0.99 MB (fits easily in ws)

#define WT_OFF    0
#define PSRC_OFF  (3 * DD * DD)
#define PDST_OFF  (PSRC_OFF + NROWS * DD)
#define PREL_OFF  (PDST_OFF + NROWS * DD)

// Transpose W (128 x 384, row-major) into three 128x128 column-major-ish
// blocks so the precompute loop reads coalesced along j.
__global__ void transposeW(const float* __restrict__ W, float* __restrict__ Wt) {
    int k = blockIdx.x;    // 0..127
    int j = threadIdx.x;   // 0..127
    Wt[0 * DD * DD + k * DD + j] = W[j * 384 + k];         // src part
    Wt[1 * DD * DD + k * DD + j] = W[j * 384 + 128 + k];   // rel part
    Wt[2 * DD * DD + k * DD + j] = W[j * 384 + 256 + k];   // dst part
}

// One block per table row (769 node rows + 2 rel rows). Builds the embedding
// row in LDS, then computes the W projection with coalesced Wt reads.
__global__ __launch_bounds__(DD) void prep(
    const float* __restrict__ gate_emb, const float* __restrict__ edge_emb,
    const float* __restrict__ b, const float* __restrict__ Wt,
    float* __restrict__ Psrc, float* __restrict__ Pdst,
    float* __restrict__ Prel) {
    __shared__ float row[DD];
    int r = blockIdx.x;
    int j = threadIdx.x;

    if (r < NROWS) {
        float v;
        if (r < 512) {
            int p = r & 255;   // input/output sinusoid tables are identical
            int i = j >> 1;
            float div = expf(-logf(10000.0f) * (2.0f * (float)i) / 128.0f);
            float ang = (float)p * div;
            v = (j & 1) ? cosf(ang) : sinf(ang);
        } else if (r < 768) {
            v = gate_emb[(r - 512) * DD + j];
        } else {
            v = 0.0f;
        }
        row[j] = v;
        __syncthreads();
        const float* Ws = Wt;                 // src part
        const float* Wd = Wt + 2 * DD * DD;   // dst part
        float s = 0.0f, d = 0.0f;
#pragma unroll 8
        for (int k = 0; k < DD; ++k) {
            float e = row[k];                          // LDS broadcast (free)
            s = fmaf(e, Ws[k * DD + j], s);            // coalesced
            d = fmaf(e, Wd[k * DD + j], d);
        }
        Psrc[r * DD + j] = s;
        Pdst[r * DD + j] = d;
    } else {
        int rr = r - NROWS;                   // 0..1
        row[j] = edge_emb[rr * DD + j];
        __syncthreads();
        const float* Wr = Wt + 1 * DD * DD;   // rel part
        float s = b[j];
#pragma unroll 8
        for (int k = 0; k < DD; ++k) s = fmaf(row[k], Wr[k * DD + j], s);
        Prel[rr * DD + j] = s;
    }
}

// out[t] = Psrc[fs(t)] + Prel[rel(t)] + Pdst[fd(t)]
// Block = 256 threads = 8 lane-groups of 32; block covers 64 rows, 8 rows per
// thread. Indices are staged ONCE per block through LDS (coalesced loads by
// threads 0..63, packed into one int), so the per-row cost is just 2 table
// gathers + 1 nt store. Prel has only 2 rows: both are loaded per-thread and
// selected with cndmask instead of gathered.
__global__ __launch_bounds__(256) void gather_add(
    const int* __restrict__ src_idx, const int* __restrict__ src_type,
    const int* __restrict__ rel, const int* __restrict__ dst_idx,
    const int* __restrict__ dst_type,
    const vfloat4* __restrict__ Psrc, const vfloat4* __restrict__ Pdst,
    const vfloat4* __restrict__ Prel, vfloat4* __restrict__ out) {
    __shared__ int spk[64];
    int tid  = threadIdx.x;
    int lane = tid & 31;                 // which float4 of the 128-dim row
    int grp  = tid >> 5;                 // 0..7
    int rowBase = blockIdx.x * 64;

    if (tid < 64) {
        int t = rowBase + tid;           // coalesced idx loads for 64 rows
        int s = src_type[t], d = dst_type[t];
        int fs = (s == 3) ? 768 : s * 256 + src_idx[t];   // zero row = 768
        int fd = (d == 3) ? 768 : d * 256 + dst_idx[t];
        spk[tid] = fs | (fd << 10) | (rel[t] << 20);
    }
    // Both rel rows (incl. bias) live in L1/L2 — load once, select per row.
    vfloat4 rel0 = Prel[lane];
    vfloat4 rel1 = Prel[32 + lane];
    __syncthreads();

    int pk[8];
#pragma unroll
    for (int i = 0; i < 8; ++i) pk[i] = spk[grp + 8 * i];   // LDS broadcast

    vfloat4 a[8], c[8];
#pragma unroll
    for (int i = 0; i < 8; ++i) a[i] = Psrc[(pk[i] & 1023) * 32 + lane];
#pragma unroll
    for (int i = 0; i < 8; ++i) c[i] = Pdst[((pk[i] >> 10) & 1023) * 32 + lane];

#pragma unroll
    for (int i = 0; i < 8; ++i) {
        vfloat4 o = a[i] + c[i] + ((pk[i] >> 20) ? rel1 : rel0);
        // Nontemporal: don't let the 256MB output stream evict the hot
        // P-tables in L2.
        __builtin_nontemporal_store(o, &out[(rowBase + grp + 8 * i) * 32 + lane]);
    }
}

extern "C" void kernel_launch(void* const* d_in, const int* in_sizes, int n_in,
                              void* d_out, int out_size, void* d_ws, size_t ws_size,
                              hipStream_t stream) {
    const float* gate_emb = (const float*)d_in[0];
    const float* edge_emb = (const float*)d_in[1];
    const float* W        = (const float*)d_in[2];
    const float* b        = (const float*)d_in[3];
    const int* src_idx    = (const int*)d_in[4];
    const int* src_type   = (const int*)d_in[5];
    const int* rel        = (const int*)d_in[6];
    const int* dst_idx    = (const int*)d_in[7];
    const int* dst_type   = (const int*)d_in[8];
    // d_in[9], d_in[10]: num_input_nodes / num_output_nodes == 256 (fixed)

    float* ws   = (float*)d_ws;
    float* Wt   = ws + WT_OFF;
    float* Psrc = ws + PSRC_OFF;
    float* Pdst = ws + PDST_OFF;
    float* Prel = ws + PREL_OFF;

    transposeW<<<DD, DD, 0, stream>>>(W, Wt);
    prep<<<NROWS + 2, DD, 0, stream>>>(gate_emb, edge_emb, b, Wt,
                                       Psrc, Pdst, Prel);
    gather_add<<<T_TOTAL / 64, 256, 0, stream>>>(
        src_idx, src_type, rel, dst_idx, dst_type,
        (const vfloat4*)Psrc, (const vfloat4*)Pdst, (const vfloat4*)Prel,
        (vfloat4*)d_out);
}

// Round 3
// 319.456 us; speedup vs baseline: 1.1606x; 1.0601x over previous
//
#include <hip/hip_runtime.h>
#include <math.h>

// Problem constants (fixed by setup_inputs)
#define DD 128
#define NROWS 769          // 256 input-enc + 256 output-enc + 256 gate + 1 zero
#define T_TOTAL 524288

typedef float vfloat4 __attribute__((ext_vector_type(4)));
typedef int   vint4   __attribute__((ext_vector_type(4)));

// ws layout (floats):
//   Wt      [3][128][128] @ 0          (Wt[part][k][j] = W[j][part*128+k])
//   Psrc    [NROWS][DD]   @ 49152
//   Pdst    [NROWS][DD]   @ 49152 +  98432
//   Prel    [2][DD]       @ 49152 + 196864
//   pk      [T] ints      @ 49152 + 197120   (packed fs|fd<<10|rel<<20)
// total ~= 3 MB (fits easily in ws)

#define WT_OFF    0
#define PSRC_OFF  (3 * DD * DD)
#define PDST_OFF  (PSRC_OFF + NROWS * DD)
#define PREL_OFF  (PDST_OFF + NROWS * DD)
#define PK_OFF    (PREL_OFF + 2 * DD)

// Fused pre-pass: blocks [0,128) transpose W; blocks [128, 128+1024) pack the
// 5 index arrays into one int per row (int4-vectorized, coalesced). The two
// halves are independent and overlap in one dispatch.
__global__ __launch_bounds__(DD) void pre(
    const float* __restrict__ W, float* __restrict__ Wt,
    const int* __restrict__ src_idx, const int* __restrict__ src_type,
    const int* __restrict__ rel, const int* __restrict__ dst_idx,
    const int* __restrict__ dst_type, int* __restrict__ pk) {
    int bid = blockIdx.x;
    int tid = threadIdx.x;
    if (bid < DD) {
        int k = bid;   // 0..127
        int j = tid;   // 0..127
        Wt[0 * DD * DD + k * DD + j] = W[j * 384 + k];         // src part
        Wt[1 * DD * DD + k * DD + j] = W[j * 384 + 128 + k];   // rel part
        Wt[2 * DD * DD + k * DD + j] = W[j * 384 + 256 + k];   // dst part
    } else {
        int t4 = (bid - DD) * DD + tid;    // which int4 group of T/4
        vint4 si = ((const vint4*)src_idx)[t4];
        vint4 st = ((const vint4*)src_type)[t4];
        vint4 rl = ((const vint4*)rel)[t4];
        vint4 di = ((const vint4*)dst_idx)[t4];
        vint4 dt = ((const vint4*)dst_type)[t4];
        vint4 o;
#pragma unroll
        for (int m = 0; m < 4; ++m) {
            int fs = (st[m] == 3) ? 768 : st[m] * 256 + si[m];  // zero row 768
            int fd = (dt[m] == 3) ? 768 : dt[m] * 256 + di[m];
            o[m] = fs | (fd << 10) | (rl[m] << 20);
        }
        ((vint4*)pk)[t4] = o;
    }
}

// One block per table row (769 node rows + 2 rel rows). Builds the embedding
// row in LDS, then computes the W projection with coalesced Wt reads.
__global__ __launch_bounds__(DD) void prep(
    const float* __restrict__ gate_emb, const float* __restrict__ edge_emb,
    const float* __restrict__ b, const float* __restrict__ Wt,
    float* __restrict__ Psrc, float* __restrict__ Pdst,
    float* __restrict__ Prel) {
    __shared__ float row[DD];
    int r = blockIdx.x;
    int j = threadIdx.x;

    if (r < NROWS) {
        float v;
        if (r < 512) {
            int p = r & 255;   // input/output sinusoid tables are identical
            int i = j >> 1;
            float div = expf(-logf(10000.0f) * (2.0f * (float)i) / 128.0f);
            float ang = (float)p * div;
            v = (j & 1) ? cosf(ang) : sinf(ang);
        } else if (r < 768) {
            v = gate_emb[(r - 512) * DD + j];
        } else {
            v = 0.0f;
        }
        row[j] = v;
        __syncthreads();
        const float* Ws = Wt;                 // src part
        const float* Wd = Wt + 2 * DD * DD;   // dst part
        float s = 0.0f, d = 0.0f;
#pragma unroll 8
        for (int k = 0; k < DD; ++k) {
            float e = row[k];                          // LDS broadcast (free)
            s = fmaf(e, Ws[k * DD + j], s);            // coalesced
            d = fmaf(e, Wd[k * DD + j], d);
        }
        Psrc[r * DD + j] = s;
        Pdst[r * DD + j] = d;
    } else {
        int rr = r - NROWS;                   // 0..1
        row[j] = edge_emb[rr * DD + j];
        __syncthreads();
        const float* Wr = Wt + 1 * DD * DD;   // rel part
        float s = b[j];
#pragma unroll 8
        for (int k = 0; k < DD; ++k) s = fmaf(row[k], Wr[k * DD + j], s);
        Prel[rr * DD + j] = s;
    }
}

// out[t] = Psrc[fs(t)] + Prel[rel(t)] + Pdst[fd(t)]
// Block = 256 threads = 8 lane-groups of 32; block covers 64 rows, lane-group
// g owns the 8 contiguous rows rowBase+g*8 .. +7. Indices come pre-packed
// from the pk array (2 MB, L2-resident): 2 int4 loads replace the 5-array
// decode + LDS staging + barrier of the previous version. Prel has only 2
// rows: both loaded per-thread and selected with cndmask instead of gathered.
__global__ __launch_bounds__(256) void gather_add(
    const int* __restrict__ pk,
    const vfloat4* __restrict__ Psrc, const vfloat4* __restrict__ Pdst,
    const vfloat4* __restrict__ Prel, vfloat4* __restrict__ out) {
    int tid  = threadIdx.x;
    int lane = tid & 31;                 // which float4 of the 128-dim row
    int grp  = tid >> 5;                 // 0..7
    int rowBase = blockIdx.x * 64;

    vint4 pkA = ((const vint4*)pk)[(rowBase >> 2) + grp * 2];
    vint4 pkB = ((const vint4*)pk)[(rowBase >> 2) + grp * 2 + 1];
    // Both rel rows (incl. bias) live in L1/L2 — load once, select per row.
    vfloat4 rel0 = Prel[lane];
    vfloat4 rel1 = Prel[32 + lane];

    int p[8] = {pkA[0], pkA[1], pkA[2], pkA[3],
                pkB[0], pkB[1], pkB[2], pkB[3]};

    vfloat4 a[8], c[8];
#pragma unroll
    for (int i = 0; i < 8; ++i) a[i] = Psrc[(p[i] & 1023) * 32 + lane];
#pragma unroll
    for (int i = 0; i < 8; ++i) c[i] = Pdst[((p[i] >> 10) & 1023) * 32 + lane];

    int rowT = rowBase + grp * 8;
#pragma unroll
    for (int i = 0; i < 8; ++i) {
        vfloat4 o = a[i] + c[i] + ((p[i] >> 20) ? rel1 : rel0);
        // Nontemporal: don't let the 256MB output stream evict the hot
        // P-tables in L2.
        __builtin_nontemporal_store(o, &out[(rowT + i) * 32 + lane]);
    }
}

extern "C" void kernel_launch(void* const* d_in, const int* in_sizes, int n_in,
                              void* d_out, int out_size, void* d_ws, size_t ws_size,
                              hipStream_t stream) {
    const float* gate_emb = (const float*)d_in[0];
    const float* edge_emb = (const float*)d_in[1];
    const float* W        = (const float*)d_in[2];
    const float* b        = (const float*)d_in[3];
    const int* src_idx    = (const int*)d_in[4];
    const int* src_type   = (const int*)d_in[5];
    const int* rel        = (const int*)d_in[6];
    const int* dst_idx    = (const int*)d_in[7];
    const int* dst_type   = (const int*)d_in[8];
    // d_in[9], d_in[10]: num_input_nodes / num_output_nodes == 256 (fixed)

    float* ws   = (float*)d_ws;
    float* Wt   = ws + WT_OFF;
    float* Psrc = ws + PSRC_OFF;
    float* Pdst = ws + PDST_OFF;
    float* Prel = ws + PREL_OFF;
    int*   pk   = (int*)(ws + PK_OFF);

    // pre: 128 transpose blocks + T/(128*4)=1024 pack blocks, one dispatch.
    pre<<<DD + T_TOTAL / (DD * 4), DD, 0, stream>>>(
        W, Wt, src_idx, src_type, rel, dst_idx, dst_type, pk);
    prep<<<NROWS + 2, DD, 0, stream>>>(gate_emb, edge_emb, b, Wt,
                                       Psrc, Pdst, Prel);
    gather_add<<<T_TOTAL / 64, 256, 0, stream>>>(
        pk, (const vfloat4*)Psrc, (const vfloat4*)Pdst,
        (const vfloat4*)Prel, (vfloat4*)d_out);
}